// Round 1
// 316.039 us; speedup vs baseline: 1.0121x; 1.0121x over previous
//
#include <hip/hip_runtime.h>
#include <hip/hip_bf16.h>

// BinaryMoSLinear: B=4, S=2048 -> N=8192 rows; H=O=4096; E=4.
#define H_DIM 4096
#define O_DIM 4096
#define N_ROWS 8192

typedef __bf16 bf16x8 __attribute__((ext_vector_type(8)));
typedef float  f32x4  __attribute__((ext_vector_type(4)));

__device__ __forceinline__ unsigned short f32_bf16_rne(float f) {
    unsigned int u = __builtin_bit_cast(unsigned int, f);
    u += 0x7FFFu + ((u >> 16) & 1u);
    return (unsigned short)(u >> 16);
}

__device__ __forceinline__ void gload_lds16(const unsigned short* g, unsigned short* l) {
    __builtin_amdgcn_global_load_lds((const __attribute__((address_space(1))) void*)g,
                                     (__attribute__((address_space(3))) void*)l,
                                     16, 0, 0);
}

// ---------------------------------------------------------------------------
// Kernel 1: bw = sign(weight) as bf16 (+1.0 / -1.0 / 0.0).
// ---------------------------------------------------------------------------
__global__ void __launch_bounds__(256) sign_kernel(const float* __restrict__ w,
                                                   unsigned short* __restrict__ bw) {
    size_t i = ((size_t)blockIdx.x * 256 + threadIdx.x) * 4;
    float4 v = *reinterpret_cast<const float4*>(w + i);
    ushort4 o;
    o.x = v.x > 0.f ? 0x3F80 : (v.x < 0.f ? 0xBF80 : 0);
    o.y = v.y > 0.f ? 0x3F80 : (v.y < 0.f ? 0xBF80 : 0);
    o.z = v.z > 0.f ? 0x3F80 : (v.z < 0.f ? 0xBF80 : 0);
    o.w = v.w > 0.f ? 0x3F80 : (v.w < 0.f ? 0xBF80 : 0);
    *reinterpret_cast<ushort4*>(bw + i) = o;
}

// ---------------------------------------------------------------------------
// Kernel 2: router softmax -> rw[n][4]; xs = bf16(x * (rw @ in_channel_scale)).
// ---------------------------------------------------------------------------
__global__ void __launch_bounds__(256) route_scale_kernel(
    const float* __restrict__ x, const float* __restrict__ gate_w,
    const float* __restrict__ ics, float* __restrict__ rw_out,
    unsigned short* __restrict__ xs_out)
{
    __shared__ float red[4][4];
    const int n = blockIdx.x;
    const int t = threadIdx.x;
    const float* xr = x + (size_t)n * H_DIM;

    float4 xv[4];
    float lg[4] = {0.f, 0.f, 0.f, 0.f};
#pragma unroll
    for (int c = 0; c < 4; ++c) {
        const int idx = c * 1024 + t * 4;
        xv[c] = *reinterpret_cast<const float4*>(xr + idx);
#pragma unroll
        for (int e = 0; e < 4; ++e) {
            float4 g = *reinterpret_cast<const float4*>(gate_w + e * H_DIM + idx);
            lg[e] += xv[c].x * g.x + xv[c].y * g.y + xv[c].z * g.z + xv[c].w * g.w;
        }
    }
#pragma unroll
    for (int e = 0; e < 4; ++e) {
#pragma unroll
        for (int off = 1; off < 64; off <<= 1)
            lg[e] += __shfl_xor(lg[e], off, 64);
    }
    if ((t & 63) == 0) {
        const int w = t >> 6;
        red[w][0] = lg[0]; red[w][1] = lg[1]; red[w][2] = lg[2]; red[w][3] = lg[3];
    }
    __syncthreads();
    const float l0 = red[0][0] + red[1][0] + red[2][0] + red[3][0];
    const float l1 = red[0][1] + red[1][1] + red[2][1] + red[3][1];
    const float l2 = red[0][2] + red[1][2] + red[2][2] + red[3][2];
    const float l3 = red[0][3] + red[1][3] + red[2][3] + red[3][3];
    const float m  = fmaxf(fmaxf(l0, l1), fmaxf(l2, l3));
    const float p0 = expf(l0 - m), p1 = expf(l1 - m), p2 = expf(l2 - m), p3 = expf(l3 - m);
    const float inv = 1.f / (p0 + p1 + p2 + p3);
    const float w0 = p0 * inv, w1 = p1 * inv, w2 = p2 * inv, w3 = p3 * inv;
    if (t == 0) {
        float4 wv = make_float4(w0, w1, w2, w3);
        *reinterpret_cast<float4*>(rw_out + (size_t)n * 4) = wv;
    }
#pragma unroll
    for (int c = 0; c < 4; ++c) {
        const int idx = c * 1024 + t * 4;
        float4 i0 = *reinterpret_cast<const float4*>(ics + 0 * H_DIM + idx);
        float4 i1 = *reinterpret_cast<const float4*>(ics + 1 * H_DIM + idx);
        float4 i2 = *reinterpret_cast<const float4*>(ics + 2 * H_DIM + idx);
        float4 i3 = *reinterpret_cast<const float4*>(ics + 3 * H_DIM + idx);
        const float sx = w0 * i0.x + w1 * i1.x + w2 * i2.x + w3 * i3.x;
        const float sy = w0 * i0.y + w1 * i1.y + w2 * i2.y + w3 * i3.y;
        const float sz = w0 * i0.z + w1 * i1.z + w2 * i2.z + w3 * i3.z;
        const float sw = w0 * i0.w + w1 * i1.w + w2 * i2.w + w3 * i3.w;
        ushort4 o;
        o.x = f32_bf16_rne(xv[c].x * sx);
        o.y = f32_bf16_rne(xv[c].y * sy);
        o.z = f32_bf16_rne(xv[c].z * sz);
        o.w = f32_bf16_rne(xv[c].w * sw);
        *reinterpret_cast<ushort4*>(xs_out + (size_t)n * H_DIM + idx) = o;
    }
}

// ---------------------------------------------------------------------------
// Kernel 3: C = (xs @ bw^T) * (rw @ ocs) + bias
// 256x256 tile, 8 waves (2Mx4N), BK=32, 4-slot LDS ring (128 KiB).
//
// NEW this round: register-level fragment double-buffer. At step kt the wave
//   (a) ds_reads the fragments of slot (kt+1)&3 into the NEXT register set,
//   (b) issues the 4 global_load_lds for slice kt+3,
//   (c) runs 32 MFMA on the CURRENT register set (loaded last step -> no
//       dependency on this step's LDS reads: LDS service overlaps MFMA).
// Ledger tightened vmcnt(8)->vmcnt(4): at end of step kt the outstanding
// calls are slices kt+2 (staged at kt-1) and kt+3 (staged at kt) = 8;
// vmcnt(4) retires slice kt+2, which step kt+1 prefetch-reads. Slice kt+3
// still has ~2 full K-steps of flight before its vmcnt -> never drains
// until kt=125. Cur/nxt rotation via unroll-by-2 with NAMED register sets
// (no runtime-indexed frag arrays -> no scratch).
//
// LDS map (bytes): A slot s @ s*16384 (256 rows x 32 k bf16 = 64B/row);
//                  B slot s @ 65536 + s*16384. Total 131072.
// Swizzle: logical (row, chunk c of 16B) stored at physical chunk
//          c ^ ((row>>1)&3); applied on BOTH global-source and LDS-read.
// ---------------------------------------------------------------------------

#define GEMM_STEP(KT, AVC, BVC, AVN, BVN)                                         \
  {                                                                               \
    const int kt_ = (KT);                                                         \
    if (kt_ < 127) {                                                              \
      const int sb_ = ((kt_ + 1) & 3) * 16384;                                    \
      _Pragma("unroll")                                                           \
      for (int fr = 0; fr < 8; ++fr)                                              \
        AVN[fr] = *reinterpret_cast<const bf16x8*>(lds + sb_ + aOff[fr]);         \
      _Pragma("unroll")                                                           \
      for (int ni = 0; ni < 4; ++ni)                                              \
        BVN[ni] = *reinterpret_cast<const bf16x8*>(lds + 65536 + sb_ + bOff[ni]); \
    }                                                                             \
    if (kt_ + 3 < 128) {                                                          \
      const int ks_ = kt_ + 3;                                                    \
      char* sA_ = lds + (ks_ & 3) * 16384;                                        \
      char* sB_ = lds + 65536 + (ks_ & 3) * 16384;                                \
      _Pragma("unroll")                                                           \
      for (int j = 0; j < 2; ++j) {                                               \
        gload_lds16(gA + ((size_t)j * 128) * H_DIM + ks_ * 32,                    \
                    (unsigned short*)(sA_ + j * 8192 + wv * 1024));               \
        gload_lds16(gB + ((size_t)j * 128) * H_DIM + ks_ * 32,                    \
                    (unsigned short*)(sB_ + j * 8192 + wv * 1024));               \
      }                                                                           \
    }                                                                             \
    __builtin_amdgcn_s_setprio(1);                                                \
    _Pragma("unroll")                                                             \
    for (int fr = 0; fr < 8; ++fr)                                                \
      _Pragma("unroll")                                                           \
      for (int ni = 0; ni < 4; ++ni)                                              \
        acc[fr][ni] = __builtin_amdgcn_mfma_f32_16x16x32_bf16(AVC[fr], BVC[ni],   \
                                                              acc[fr][ni], 0, 0, 0); \
    __builtin_amdgcn_s_setprio(0);                                                \
    if (kt_ <= 124)      asm volatile("s_waitcnt vmcnt(4)" ::: "memory");         \
    else if (kt_ == 125) asm volatile("s_waitcnt vmcnt(0)" ::: "memory");         \
    if (kt_ < 127) __builtin_amdgcn_s_barrier();                                  \
  }

__global__ void __launch_bounds__(512, 2) gemm_bin_kernel(
    const unsigned short* __restrict__ xs,   // [N_ROWS][H] bf16
    const unsigned short* __restrict__ bw,   // [O][H] bf16 (row = output col)
    const float* __restrict__ rw,            // [N_ROWS][4]
    const float* __restrict__ ocs,           // [4][O]
    const float* __restrict__ bias,          // [O]
    float* __restrict__ out)                 // [N_ROWS][O]
{
    __shared__ __align__(16) char lds[131072];

    const int t  = threadIdx.x;
    const int wv = t >> 6;
    const int ln = t & 63;
    const int wr = wv >> 2;          // 0..1 -> 128-row half
    const int wc = wv & 3;           // 0..3 -> 64-col quarter

    // T1: bijective XCD swizzle (512 blocks, 512%8==0)
    const int bid = blockIdx.x;
    const int swz = (bid & 7) * 64 + (bid >> 3);
    const int rowBase = (swz >> 4) * 256;    // 32 M-tiles
    const int colBase = (swz & 15) * 256;    // 16 N-tiles

    // staging thread map: r = t>>2 (row within 128-row call), physical chunk
    // t&3 holds logical chunk (t&3)^((t>>3)&3)  [= (t&3)^((row>>1)&3)]
    const int s_r  = t >> 2;
    const int s_cl = (t & 3) ^ ((t >> 3) & 3);
    const unsigned short* gA = xs + (size_t)(rowBase + s_r) * H_DIM + s_cl * 8;
    const unsigned short* gB = bw + (size_t)(colBase + s_r) * H_DIM + s_cl * 8;

    // read-side fragment byte offsets within a slot (loop-invariant)
    int aOff[8], bOff[4];
#pragma unroll
    for (int fr = 0; fr < 8; ++fr) {
        const int row = wr * 128 + fr * 16 + (ln & 15);
        aOff[fr] = row * 64 + (((ln >> 4) ^ ((row >> 1) & 3)) << 4);
    }
#pragma unroll
    for (int ni = 0; ni < 4; ++ni) {
        const int row = wc * 64 + ni * 16 + (ln & 15);
        bOff[ni] = row * 64 + (((ln >> 4) ^ ((row >> 1) & 3)) << 4);
    }

    f32x4 acc[8][4];
#pragma unroll
    for (int i = 0; i < 8; ++i)
#pragma unroll
        for (int j = 0; j < 4; ++j) acc[i][j] = (f32x4){0.f, 0.f, 0.f, 0.f};

    // ---- prologue: stage slices 0,1,2 ----
#pragma unroll
    for (int kt = 0; kt < 3; ++kt) {
        char* sA = lds + kt * 16384;
        char* sB = lds + 65536 + kt * 16384;
#pragma unroll
        for (int j = 0; j < 2; ++j) {
            gload_lds16(gA + ((size_t)j * 128) * H_DIM + kt * 32,
                        (unsigned short*)(sA + j * 8192 + wv * 1024));
            gload_lds16(gB + ((size_t)j * 128) * H_DIM + kt * 32,
                        (unsigned short*)(sB + j * 8192 + wv * 1024));
        }
    }
    // slices 0 and 1 must be resident (slot 0 feeds step 0's MFMA preload,
    // slot 1 feeds step 0's nxt-prefetch); only slice 2's 4 calls may remain.
    asm volatile("s_waitcnt vmcnt(4)" ::: "memory");
    __builtin_amdgcn_s_barrier();

    // preload CURRENT register set from slot 0
    bf16x8 avA[8], bvA[4], avB[8], bvB[4];
#pragma unroll
    for (int fr = 0; fr < 8; ++fr)
        avA[fr] = *reinterpret_cast<const bf16x8*>(lds + aOff[fr]);
#pragma unroll
    for (int ni = 0; ni < 4; ++ni)
        bvA[ni] = *reinterpret_cast<const bf16x8*>(lds + 65536 + bOff[ni]);

    // ---- main loop: 128 K-steps, unrolled by 2 for cur/nxt rotation ----
    for (int kt = 0; kt < 128; kt += 2) {
        GEMM_STEP(kt,     avA, bvA, avB, bvB);
        GEMM_STEP(kt + 1, avB, bvB, avA, bvA);
    }

    // ---- epilogue: y = acc * (rw . ocs[:,col]) + bias ----
    float oce[4][4], bve[4];
    int cole[4];
#pragma unroll
    for (int ni = 0; ni < 4; ++ni) {
        const int col = colBase + wc * 64 + ni * 16 + (ln & 15);
        cole[ni] = col;
        oce[ni][0] = ocs[0 * O_DIM + col];
        oce[ni][1] = ocs[1 * O_DIM + col];
        oce[ni][2] = ocs[2 * O_DIM + col];
        oce[ni][3] = ocs[3 * O_DIM + col];
        bve[ni] = bias[col];
    }
#pragma unroll
    for (int fr = 0; fr < 8; ++fr) {
        float4 rwv[4];
        int rowe[4];
#pragma unroll
        for (int j = 0; j < 4; ++j) {
            const int row = rowBase + wr * 128 + fr * 16 + (ln >> 4) * 4 + j;
            rowe[j] = row;
            rwv[j] = *reinterpret_cast<const float4*>(rw + (size_t)row * 4);
        }
#pragma unroll
        for (int ni = 0; ni < 4; ++ni) {
#pragma unroll
            for (int j = 0; j < 4; ++j) {
                const float os = rwv[j].x * oce[ni][0] + rwv[j].y * oce[ni][1] +
                                 rwv[j].z * oce[ni][2] + rwv[j].w * oce[ni][3];
                out[(size_t)rowe[j] * O_DIM + cole[ni]] = acc[fr][ni][j] * os + bve[ni];
            }
        }
    }
}

// ---------------------------------------------------------------------------
extern "C" void kernel_launch(void* const* d_in, const int* in_sizes, int n_in,
                              void* d_out, int out_size, void* d_ws, size_t ws_size,
                              hipStream_t stream) {
    const float* x      = (const float*)d_in[0];
    const float* weight = (const float*)d_in[1];
    const float* bias   = (const float*)d_in[2];
    const float* gate_w = (const float*)d_in[3];
    const float* ics    = (const float*)d_in[4];
    const float* ocs    = (const float*)d_in[5];
    float* out = (float*)d_out;

    unsigned short* xs = (unsigned short*)d_ws;                      // [N][H] bf16
    unsigned short* bw = xs + (size_t)N_ROWS * H_DIM;                // [O][H] bf16
    float* rw = (float*)(bw + (size_t)O_DIM * H_DIM);                // [N][4]

    sign_kernel<<<(O_DIM * H_DIM) / (256 * 4), 256, 0, stream>>>(weight, bw);
    route_scale_kernel<<<N_ROWS, 256, 0, stream>>>(x, gate_w, ics, rw, xs);
    gemm_bin_kernel<<<(N_ROWS / 256) * (O_DIM / 256), 512, 0, stream>>>(xs, bw, rw, ocs, bias, out);
}

// Round 2
// 314.928 us; speedup vs baseline: 1.0156x; 1.0035x over previous
//
#include <hip/hip_runtime.h>
#include <hip/hip_bf16.h>

// BinaryMoSLinear: B=4, S=2048 -> N=8192 rows; H=O=4096; E=4.
#define H_DIM 4096
#define O_DIM 4096
#define N_ROWS 8192

typedef __bf16 bf16x8 __attribute__((ext_vector_type(8)));
typedef float  f32x4  __attribute__((ext_vector_type(4)));

__device__ __forceinline__ unsigned short f32_bf16_rne(float f) {
    unsigned int u = __builtin_bit_cast(unsigned int, f);
    u += 0x7FFFu + ((u >> 16) & 1u);
    return (unsigned short)(u >> 16);
}

__device__ __forceinline__ void gload_lds16(const unsigned short* g, unsigned short* l) {
    __builtin_amdgcn_global_load_lds((const __attribute__((address_space(1))) void*)g,
                                     (__attribute__((address_space(3))) void*)l,
                                     16, 0, 0);
}

// ---------------------------------------------------------------------------
// Kernel 1: bw = sign(weight) as bf16 (+1.0 / -1.0 / 0.0).
// ---------------------------------------------------------------------------
__global__ void __launch_bounds__(256) sign_kernel(const float* __restrict__ w,
                                                   unsigned short* __restrict__ bw) {
    size_t i = ((size_t)blockIdx.x * 256 + threadIdx.x) * 4;
    float4 v = *reinterpret_cast<const float4*>(w + i);
    ushort4 o;
    o.x = v.x > 0.f ? 0x3F80 : (v.x < 0.f ? 0xBF80 : 0);
    o.y = v.y > 0.f ? 0x3F80 : (v.y < 0.f ? 0xBF80 : 0);
    o.z = v.z > 0.f ? 0x3F80 : (v.z < 0.f ? 0xBF80 : 0);
    o.w = v.w > 0.f ? 0x3F80 : (v.w < 0.f ? 0xBF80 : 0);
    *reinterpret_cast<ushort4*>(bw + i) = o;
}

// ---------------------------------------------------------------------------
// Kernel 2: router softmax -> rw[n][4]; xs = bf16(x * (rw @ in_channel_scale)).
// ---------------------------------------------------------------------------
__global__ void __launch_bounds__(256) route_scale_kernel(
    const float* __restrict__ x, const float* __restrict__ gate_w,
    const float* __restrict__ ics, float* __restrict__ rw_out,
    unsigned short* __restrict__ xs_out)
{
    __shared__ float red[4][4];
    const int n = blockIdx.x;
    const int t = threadIdx.x;
    const float* xr = x + (size_t)n * H_DIM;

    float4 xv[4];
    float lg[4] = {0.f, 0.f, 0.f, 0.f};
#pragma unroll
    for (int c = 0; c < 4; ++c) {
        const int idx = c * 1024 + t * 4;
        xv[c] = *reinterpret_cast<const float4*>(xr + idx);
#pragma unroll
        for (int e = 0; e < 4; ++e) {
            float4 g = *reinterpret_cast<const float4*>(gate_w + e * H_DIM + idx);
            lg[e] += xv[c].x * g.x + xv[c].y * g.y + xv[c].z * g.z + xv[c].w * g.w;
        }
    }
#pragma unroll
    for (int e = 0; e < 4; ++e) {
#pragma unroll
        for (int off = 1; off < 64; off <<= 1)
            lg[e] += __shfl_xor(lg[e], off, 64);
    }
    if ((t & 63) == 0) {
        const int w = t >> 6;
        red[w][0] = lg[0]; red[w][1] = lg[1]; red[w][2] = lg[2]; red[w][3] = lg[3];
    }
    __syncthreads();
    const float l0 = red[0][0] + red[1][0] + red[2][0] + red[3][0];
    const float l1 = red[0][1] + red[1][1] + red[2][1] + red[3][1];
    const float l2 = red[0][2] + red[1][2] + red[2][2] + red[3][2];
    const float l3 = red[0][3] + red[1][3] + red[2][3] + red[3][3];
    const float m  = fmaxf(fmaxf(l0, l1), fmaxf(l2, l3));
    const float p0 = expf(l0 - m), p1 = expf(l1 - m), p2 = expf(l2 - m), p3 = expf(l3 - m);
    const float inv = 1.f / (p0 + p1 + p2 + p3);
    const float w0 = p0 * inv, w1 = p1 * inv, w2 = p2 * inv, w3 = p3 * inv;
    if (t == 0) {
        float4 wv = make_float4(w0, w1, w2, w3);
        *reinterpret_cast<float4*>(rw_out + (size_t)n * 4) = wv;
    }
#pragma unroll
    for (int c = 0; c < 4; ++c) {
        const int idx = c * 1024 + t * 4;
        float4 i0 = *reinterpret_cast<const float4*>(ics + 0 * H_DIM + idx);
        float4 i1 = *reinterpret_cast<const float4*>(ics + 1 * H_DIM + idx);
        float4 i2 = *reinterpret_cast<const float4*>(ics + 2 * H_DIM + idx);
        float4 i3 = *reinterpret_cast<const float4*>(ics + 3 * H_DIM + idx);
        const float sx = w0 * i0.x + w1 * i1.x + w2 * i2.x + w3 * i3.x;
        const float sy = w0 * i0.y + w1 * i1.y + w2 * i2.y + w3 * i3.y;
        const float sz = w0 * i0.z + w1 * i1.z + w2 * i2.z + w3 * i3.z;
        const float sw = w0 * i0.w + w1 * i1.w + w2 * i2.w + w3 * i3.w;
        ushort4 o;
        o.x = f32_bf16_rne(xv[c].x * sx);
        o.y = f32_bf16_rne(xv[c].y * sy);
        o.z = f32_bf16_rne(xv[c].z * sz);
        o.w = f32_bf16_rne(xv[c].w * sw);
        *reinterpret_cast<ushort4*>(xs_out + (size_t)n * H_DIM + idx) = o;
    }
}

// ---------------------------------------------------------------------------
// Kernel 3: C = (xs @ bw^T) * (rw @ ocs) + bias  — m201-style 8-phase schedule
//
// 256x256 tile, 8 waves (2Mx4N), BK=64, 2 LDS slots (tiles alternate even/odd).
// LDS map (bytes): slot s = s*65536; A half h @ +h*16384; B half h @ +32768+h*16384.
//   Row r (0..127) of a half = 128 B (8 chunks of 16 B); physical chunk
//   p = c ^ (r&7) (XOR involution; applied on pre-swizzled global source AND
//   on LDS read -> conflict-free ds_read_b128 / linear gload_lds dest).
//
// Per iteration it: compute K-tiles T0=2it (slot0, phases P1-P4) and
// T1=2it+1 (slot1, P5-P8). Quadrants: P1(fh0,n0) P2(fh0,n1) P3(fh1,n1)
// P4(fh1,n0) — A-set reloaded at P1/P3/P5/P7, B-sets Ba(n0) Bb(n1) held.
// ds_reads/phase: 12,4,8,0,12,4,8,0.
//
// Stage schedule (2 gload calls/phase; earliest-legal, overwrite-join listed):
//   P1: A0(2it+1)  [A(2it-1) last read P7', join P7'/P8' barriers]
//   P2: A1(2it+1)
//   P3: B0(2it+2)  [B(2it) last read P2, join P2 post-barrier]
//   P4: B1(2it+2)
//   P5: A0(2it+2)  [A(2it) last read P3, join P3/P4 barriers]
//   P6: A1(2it+2)
//   P7: B0(2it+3)  [B(2it+1) last read P6, join P6 post-barrier]
//   P8: B1(2it+3)
// Gates (counted, never 0 in steady state):
//   P4 pre-barrier vmcnt(4): leaves {P3,P4} flying; guarantees A0/A1(2it+1)
//     (issued P1/P2) + B(2it+1) (issued P7'/P8') landed -> P5-P7 reads safe.
//   P8 pre-barrier vmcnt(4): leaves {P7,P8} flying; guarantees all of tile
//     2it+2 (issued P3-P6) landed -> next-iter P1-P4 reads safe.
//   Every staged call gets >=2 phases of flight before its gate.
// Boundary: it=0 skips P1/P2 (tile1 prologue-staged); it=31 skips P3-P8
//   stages and drains with vmcnt(0) at P4.
// Phase body: reads; stage; [gate]; s_barrier; lgkmcnt(0)+sched_barrier(0)
//   (rule #18); setprio(1); 16 MFMA; setprio(0); s_barrier.
// ---------------------------------------------------------------------------

#define LD8(OFF) (*reinterpret_cast<const bf16x8*>(lds + (OFF)))

#define READ_A(FH, SB)                                                          \
  _Pragma("unroll") for (int f_ = 0; f_ < 4; ++f_) {                            \
    Av[f_*2+0] = LD8((SB) + aB0 + ((FH)*4 + f_) * 2048);                        \
    Av[f_*2+1] = LD8((SB) + aB1 + ((FH)*4 + f_) * 2048);                        \
  }

#define READ_B(SET, NH, SB)                                                     \
  _Pragma("unroll") for (int n_ = 0; n_ < 2; ++n_) {                            \
    SET[n_*2+0] = LD8((SB) + bB0 + ((NH)*2 + n_) * 2048);                       \
    SET[n_*2+1] = LD8((SB) + bB1 + ((NH)*2 + n_) * 2048);                       \
  }

#define MFMA16(FH, NH, BS)                                                      \
  _Pragma("unroll") for (int f_ = 0; f_ < 4; ++f_)                              \
  _Pragma("unroll") for (int n_ = 0; n_ < 2; ++n_)                              \
  _Pragma("unroll") for (int k_ = 0; k_ < 2; ++k_)                              \
    acc[(FH)*4+f_][(NH)*2+n_] = __builtin_amdgcn_mfma_f32_16x16x32_bf16(        \
        Av[f_*2+k_], BS[n_*2+k_], acc[(FH)*4+f_][(NH)*2+n_], 0, 0, 0);

// stage one half-tile (128 rows x 64 k): matrix GPTR (ISB: 0=A,1=B), half H_,
// K-tile KT -> slot KT&1. 2 gload calls (rows 0-63, 64-127 of the half).
#define STAGE_HALF(GPTR, ISB, H_, KT)                                           \
  { char* d_ = lds + ((KT)&1)*65536 + (ISB)*32768 + (H_)*16384 + wv*1024;       \
    const unsigned short* s_ = (GPTR) + (size_t)((H_)*128) * H_DIM + (KT)*64;   \
    gload_lds16(s_, (unsigned short*)d_);                                       \
    gload_lds16(s_ + (size_t)64 * H_DIM, (unsigned short*)(d_ + 8192)); }

#define PRE_MFMA                                                                \
  __builtin_amdgcn_s_barrier();                                                 \
  asm volatile("s_waitcnt lgkmcnt(0)" ::: "memory");                            \
  __builtin_amdgcn_sched_barrier(0);                                            \
  __builtin_amdgcn_s_setprio(1);

#define POST_MFMA                                                               \
  __builtin_amdgcn_s_setprio(0);                                                \
  __builtin_amdgcn_s_barrier();

__global__ void __launch_bounds__(512, 2) gemm_bin_kernel(
    const unsigned short* __restrict__ xs,   // [N_ROWS][H] bf16
    const unsigned short* __restrict__ bw,   // [O][H] bf16 (row = output col)
    const float* __restrict__ rw,            // [N_ROWS][4]
    const float* __restrict__ ocs,           // [4][O]
    const float* __restrict__ bias,          // [O]
    float* __restrict__ out)                 // [N_ROWS][O]
{
    __shared__ __align__(16) char lds[131072];

    const int t  = threadIdx.x;
    const int wv = t >> 6;
    const int ln = t & 63;
    const int wr = wv >> 2;          // 0..1 -> 128-row half
    const int wc = wv & 3;           // 0..3 -> 64-col quarter

    // T1: bijective XCD swizzle (512 blocks, 512%8==0)
    const int bid = blockIdx.x;
    const int swz = (bid & 7) * 64 + (bid >> 3);
    const int rowBase = (swz >> 4) * 256;    // 32 M-tiles
    const int colBase = (swz & 15) * 256;    // 16 N-tiles

    // staging thread map: row r = j*64 + (t>>3), physical chunk t&7 holds
    // logical chunk (t&7)^((t>>3)&7)  [= p ^ (r&7), involution]
    const int s_r  = t >> 3;
    const int s_cl = (t & 7) ^ ((t >> 3) & 7);
    const unsigned short* gA = xs + (size_t)(rowBase + s_r) * H_DIM + s_cl * 8;
    const unsigned short* gB = bw + (size_t)(colBase + s_r) * H_DIM + s_cl * 8;

    // read-side per-lane bases (r&7 == ln&7 since all row strides are mult. of 8)
    const int sw0 = (((ln >> 4) ^ (ln & 7)) << 4);        // kh=0 chunk byte
    const int sw1 = (((4 | (ln >> 4)) ^ (ln & 7)) << 4);  // kh=1 chunk byte
    const int aB0 = wr * 16384 + (ln & 15) * 128 + sw0;
    const int aB1 = wr * 16384 + (ln & 15) * 128 + sw1;
    const int bB0 = 32768 + (wc >> 1) * 16384 + (wc & 1) * 8192 + (ln & 15) * 128 + sw0;
    const int bB1 = 32768 + (wc >> 1) * 16384 + (wc & 1) * 8192 + (ln & 15) * 128 + sw1;

    f32x4 acc[8][4];
#pragma unroll
    for (int i = 0; i < 8; ++i)
#pragma unroll
        for (int j = 0; j < 4; ++j) acc[i][j] = (f32x4){0.f, 0.f, 0.f, 0.f};

    bf16x8 Av[8], Ba[4], Bb[4];

    // ---- prologue: stage tiles 0 (slot0) and 1 (slot1), 16 calls ----
    STAGE_HALF(gA, 0, 0, 0); STAGE_HALF(gA, 0, 1, 0);
    STAGE_HALF(gB, 1, 0, 0); STAGE_HALF(gB, 1, 1, 0);
    STAGE_HALF(gA, 0, 0, 1); STAGE_HALF(gA, 0, 1, 1);
    STAGE_HALF(gB, 1, 0, 1); STAGE_HALF(gB, 1, 1, 1);
    asm volatile("s_waitcnt vmcnt(8)" ::: "memory");   // tile0 landed; tile1 flying
    __builtin_amdgcn_s_barrier();

    // ---- main loop: 32 iterations x 2 K-tiles x 4 phases ----
    for (int it = 0; it < 32; ++it) {
        const int T1 = 2 * it + 1, T2 = 2 * it + 2, T3 = 2 * it + 3;

        // P1: (fh0,n0) of T0  [12 reads]
        READ_A(0, 0); READ_B(Ba, 0, 0);
        if (it >= 1) STAGE_HALF(gA, 0, 0, T1);
        PRE_MFMA; MFMA16(0, 0, Ba); POST_MFMA;

        // P2: (fh0,n1) of T0  [4 reads]
        READ_B(Bb, 1, 0);
        if (it >= 1) STAGE_HALF(gA, 0, 1, T1);
        PRE_MFMA; MFMA16(0, 1, Bb); POST_MFMA;

        // P3: (fh1,n1) of T0  [8 reads]
        READ_A(1, 0);
        if (it < 31) STAGE_HALF(gB, 1, 0, T2);
        PRE_MFMA; MFMA16(1, 1, Bb); POST_MFMA;

        // P4: (fh1,n0) of T0  [0 reads] + gate
        if (it < 31) STAGE_HALF(gB, 1, 1, T2);
        if (it < 31) asm volatile("s_waitcnt vmcnt(4)" ::: "memory");
        else         asm volatile("s_waitcnt vmcnt(0)" ::: "memory");
        PRE_MFMA; MFMA16(1, 0, Ba); POST_MFMA;

        // P5: (fh0,n0) of T1  [12 reads]
        READ_A(0, 65536); READ_B(Ba, 0, 65536);
        if (it < 31) STAGE_HALF(gA, 0, 0, T2);
        PRE_MFMA; MFMA16(0, 0, Ba); POST_MFMA;

        // P6: (fh0,n1) of T1  [4 reads]
        READ_B(Bb, 1, 65536);
        if (it < 31) STAGE_HALF(gA, 0, 1, T2);
        PRE_MFMA; MFMA16(0, 1, Bb); POST_MFMA;

        // P7: (fh1,n1) of T1  [8 reads]
        READ_A(1, 65536);
        if (it < 31) STAGE_HALF(gB, 1, 0, T3);
        PRE_MFMA; MFMA16(1, 1, Bb); POST_MFMA;

        // P8: (fh1,n0) of T1  [0 reads] + gate
        if (it < 31) STAGE_HALF(gB, 1, 1, T3);
        if (it < 31) asm volatile("s_waitcnt vmcnt(4)" ::: "memory");
        PRE_MFMA; MFMA16(1, 0, Ba); POST_MFMA;
    }

    // ---- epilogue: y = acc * (rw . ocs[:,col]) + bias ----
    float oce[4][4], bve[4];
    int cole[4];
#pragma unroll
    for (int ni = 0; ni < 4; ++ni) {
        const int col = colBase + wc * 64 + ni * 16 + (ln & 15);
        cole[ni] = col;
        oce[ni][0] = ocs[0 * O_DIM + col];
        oce[ni][1] = ocs[1 * O_DIM + col];
        oce[ni][2] = ocs[2 * O_DIM + col];
        oce[ni][3] = ocs[3 * O_DIM + col];
        bve[ni] = bias[col];
    }
#pragma unroll
    for (int fr = 0; fr < 8; ++fr) {
        float4 rwv[4];
        int rowe[4];
#pragma unroll
        for (int j = 0; j < 4; ++j) {
            const int row = rowBase + wr * 128 + fr * 16 + (ln >> 4) * 4 + j;
            rowe[j] = row;
            rwv[j] = *reinterpret_cast<const float4*>(rw + (size_t)row * 4);
        }
#pragma unroll
        for (int ni = 0; ni < 4; ++ni) {
#pragma unroll
            for (int j = 0; j < 4; ++j) {
                const float os = rwv[j].x * oce[ni][0] + rwv[j].y * oce[ni][1] +
                                 rwv[j].z * oce[ni][2] + rwv[j].w * oce[ni][3];
                out[(size_t)rowe[j] * O_DIM + cole[ni]] = acc[fr][ni][j] * os + bve[ni];
            }
        }
    }
}

// ---------------------------------------------------------------------------
extern "C" void kernel_launch(void* const* d_in, const int* in_sizes, int n_in,
                              void* d_out, int out_size, void* d_ws, size_t ws_size,
                              hipStream_t stream) {
    const float* x      = (const float*)d_in[0];
    const float* weight = (const float*)d_in[1];
    const float* bias   = (const float*)d_in[2];
    const float* gate_w = (const float*)d_in[3];
    const float* ics    = (const float*)d_in[4];
    const float* ocs    = (const float*)d_in[5];
    float* out = (float*)d_out;

    unsigned short* xs = (unsigned short*)d_ws;                      // [N][H] bf16
    unsigned short* bw = xs + (size_t)N_ROWS * H_DIM;                // [O][H] bf16
    float* rw = (float*)(bw + (size_t)O_DIM * H_DIM);                // [N][4]

    sign_kernel<<<(O_DIM * H_DIM) / (256 * 4), 256, 0, stream>>>(weight, bw);
    route_scale_kernel<<<N_ROWS, 256, 0, stream>>>(x, gate_w, ics, rw, xs);
    gemm_bin_kernel<<<(N_ROWS / 256) * (O_DIM / 256), 512, 0, stream>>>(xs, bw, rw, ocs, bias, out);
}